// Round 1
// baseline (220.653 us; speedup 1.0000x reference)
//
#include <hip/hip_runtime.h>
#include <math.h>

#define N_PTS 2048
#define M_PTS 128
#define INNF  256
#define H     128

#define MIN_STDC 0.30235680f   /* 0.32*1.88973/2 */
#define MAX_STDC 2.19208680f   /* 2.32*1.88973/2 */
#define PI_F     3.14159265358979f

static __device__ __forceinline__ float silu_f(float x) {
  return x / (1.0f + __expf(-x));
}

// ---------------------------------------------------------------------------
// K0: spherical harmonics + d^2 for all (n,m) pairs.
// SH layout [n][m][12]: {1, x, y, z, s3xz, s3xy, yy-0.5(xx+zz), s3yz,
//                        0.5*s3*(zz-xx), d2, 0, 0}
// Slots 0..8 double as the K-dim rows of the "up" GEMM (CU rows 9..11 are 0).
// ---------------------------------------------------------------------------
__global__ __launch_bounds__(256) void k_sh(const float* __restrict__ gc,
                                            const float* __restrict__ cc,
                                            float* __restrict__ SH) {
  int p = blockIdx.x * 256 + threadIdx.x;     // 0 .. N*M-1
  int n = p >> 7, m = p & 127;
  float gx = gc[3*n], gy = gc[3*n+1], gz = gc[3*n+2];
  float cx = cc[3*m], cy = cc[3*m+1], cz = cc[3*m+2];
  float dx = gx - cx, dy = gy - cy, dz = gz - cz;
  float d2 = dx*dx + dy*dy + dz*dz + 3e-20f;  // ref adds 1e-20 per component
  float inv = rsqrtf(d2);
  float x = dx*inv, y = dy*inv, z = dz*inv;
  const float s3 = 1.73205080757f;
  float4 q0 = make_float4(1.0f, x, y, z);
  float4 q1 = make_float4(s3*x*z, s3*x*y, y*y - 0.5f*(x*x + z*z), s3*y*z);
  float4 q2 = make_float4(0.5f*s3*(z*z - x*x), d2, 0.0f, 0.0f);
  float4* dst = (float4*)(SH + (size_t)p * 12);
  dst[0] = q0; dst[1] = q1; dst[2] = q2;
}

// ---------------------------------------------------------------------------
// K1: hpre = silu(h @ W_pre + b_pre)  (kept in LDS), then
//     hdg[l][n][w] = (hpre @ W_down[l])[n,w] * gw[n] * coef(w) * (1/sqrt(2l+1))
// coef(w) = (2/3)/temps_w/(pi*temps_w)^1.5 folded in so the pair kernel's
// radial is just e^{-d2/t_w} * d2.
// Block: 8 rows of n, 128 threads, thread-tile 2n x 4w.
// ---------------------------------------------------------------------------
__global__ __launch_bounds__(128) void k_pre(const float* __restrict__ h,
    const float* __restrict__ W_pre, const float* __restrict__ b_pre,
    const float* __restrict__ W_down, const float* __restrict__ gw,
    float* __restrict__ hdg) {
  __shared__ float h_t[INNF * 10];   // [u][n], pad 10 keeps b64 reads aligned
  __shared__ float hp_t[H * 10];
  int t = threadIdx.x;
  int n0 = blockIdx.x * 8;
  int tgn = t >> 5;          // 0..3 -> n = 2*tgn + r
  int tgw = t & 31;          // w = 4*tgw + c

  // stage h tile transposed
  #pragma unroll
  for (int i = 0; i < 4; ++i) {
    int j = t + i * 128;               // 0..511 float4s
    int n = j >> 6, uq = (j & 63) << 2;
    float4 v = *(const float4*)(h + (size_t)(n0 + n) * INNF + uq);
    h_t[(uq+0)*10 + n] = v.x;
    h_t[(uq+1)*10 + n] = v.y;
    h_t[(uq+2)*10 + n] = v.z;
    h_t[(uq+3)*10 + n] = v.w;
  }
  __syncthreads();

  float acc[2][4] = {};
  for (int u = 0; u < INNF; ++u) {
    float2 a = *(const float2*)&h_t[u*10 + 2*tgn];
    float4 wv = *(const float4*)(W_pre + u*H + 4*tgw);
    acc[0][0] += a.x*wv.x; acc[0][1] += a.x*wv.y; acc[0][2] += a.x*wv.z; acc[0][3] += a.x*wv.w;
    acc[1][0] += a.y*wv.x; acc[1][1] += a.y*wv.y; acc[1][2] += a.y*wv.z; acc[1][3] += a.y*wv.w;
  }
  float4 bv = *(const float4*)(b_pre + 4*tgw);
  float bb[4] = {bv.x, bv.y, bv.z, bv.w};
  #pragma unroll
  for (int r = 0; r < 2; ++r)
    #pragma unroll
    for (int c = 0; c < 4; ++c) {
      float v = silu_f(acc[r][c] + bb[c]);
      hp_t[(4*tgw + c)*10 + 2*tgn + r] = v;
    }
  __syncthreads();

  // per-w radial constants (folded)
  float coef[4];
  const float stp = (MAX_STDC - MIN_STDC) / 127.0f;
  #pragma unroll
  for (int c = 0; c < 4; ++c) {
    int w = 4*tgw + c;
    float s = MIN_STDC + (float)w * stp;
    float temps = 2.0f * s * s;
    coef[c] = (2.0f/3.0f) / (temps * powf(PI_F * temps, 1.5f));
  }
  float gw2[2] = {gw[n0 + 2*tgn], gw[n0 + 2*tgn + 1]};
  const float invn0 = 1.0f, invn1 = 0.57735026919f, invn2 = 0.44721359550f;

  for (int l = 0; l < 3; ++l) {
    float a2[2][4] = {};
    for (int u = 0; u < H; ++u) {
      float2 a = *(const float2*)&hp_t[u*10 + 2*tgn];
      float4 wv = *(const float4*)(W_down + (size_t)(l*H + u)*H + 4*tgw);
      a2[0][0] += a.x*wv.x; a2[0][1] += a.x*wv.y; a2[0][2] += a.x*wv.z; a2[0][3] += a.x*wv.w;
      a2[1][0] += a.y*wv.x; a2[1][1] += a.y*wv.y; a2[1][2] += a.y*wv.z; a2[1][3] += a.y*wv.w;
    }
    float invn = (l == 0) ? invn0 : (l == 1 ? invn1 : invn2);
    #pragma unroll
    for (int r = 0; r < 2; ++r) {
      float sc = gw2[r] * invn;
      float4 o = make_float4(a2[r][0]*sc*coef[0], a2[r][1]*sc*coef[1],
                             a2[r][2]*sc*coef[2], a2[r][3]*sc*coef[3]);
      *(float4*)(hdg + ((size_t)l*N_PTS + n0 + 2*tgn + r)*H + 4*tgw) = o;
    }
  }
}

// ---------------------------------------------------------------------------
// K2: the pair loop ("down"). Thread = w-channel, block = 4 m's x 128 n's.
// acc[m][li] over n; SH reads are wave-uniform (scalarizable), hdg coalesced.
// c_part[s][m][li][w] partials (S=16 n-chunks).
// ---------------------------------------------------------------------------
__global__ __launch_bounds__(128) void k_down(const float* __restrict__ SH,
    const float* __restrict__ hdg, float* __restrict__ c_part) {
  int t = threadIdx.x;
  int m0 = blockIdx.x * 4;
  int s  = blockIdx.y;
  int n0 = s * 128;
  const float stp = (MAX_STDC - MIN_STDC) / 127.0f;
  float sw = MIN_STDC + (float)t * stp;
  float invt = 1.0f / (2.0f * sw * sw);
  float acc[4][9] = {};
  for (int n = n0; n < n0 + 128; ++n) {
    float a0 = hdg[(size_t)n*H + t];
    float a1 = hdg[((size_t)N_PTS   + n)*H + t];
    float a2 = hdg[((size_t)2*N_PTS + n)*H + t];
    const float* shb = SH + ((size_t)n*M_PTS + m0) * 12;
    #pragma unroll
    for (int mm = 0; mm < 4; ++mm) {
      float4 q0 = *(const float4*)(shb + mm*12);
      float4 q1 = *(const float4*)(shb + mm*12 + 4);
      float4 q2 = *(const float4*)(shb + mm*12 + 8);
      float e  = __expf(-q2.y * invt);
      float rp = e * q2.y;                 // coef already folded into hdg
      float t0 = a0*rp, t1 = a1*rp, t2 = a2*rp;
      acc[mm][0] += t0;
      acc[mm][1] += t1*q0.y; acc[mm][2] += t1*q0.z; acc[mm][3] += t1*q0.w;
      acc[mm][4] += t2*q1.x; acc[mm][5] += t2*q1.y;
      acc[mm][6] += t2*q1.z; acc[mm][7] += t2*q1.w;
      acc[mm][8] += t2*q2.x;
    }
  }
  #pragma unroll
  for (int mm = 0; mm < 4; ++mm)
    #pragma unroll
    for (int li = 0; li < 9; ++li)
      c_part[(((size_t)s*M_PTS + m0 + mm)*9 + li)*H + t] = acc[mm][li];
}

// ---------------------------------------------------------------------------
// K3: reduce partials over s, apply W_up + up-norm -> CU[m][12][w] (rows 9..11
// zeroed so the up GEMM can run a flat K=1536).
// ---------------------------------------------------------------------------
__global__ __launch_bounds__(128) void k_cu(const float* __restrict__ c_part,
    const float* __restrict__ W_up, float* __restrict__ CU) {
  __shared__ float c_lds[9 * H];
  int t = threadIdx.x, m = blockIdx.x;
  #pragma unroll
  for (int k = 0; k < 9; ++k) {
    float v = 0.0f;
    #pragma unroll
    for (int s = 0; s < 16; ++s)
      v += c_part[(((size_t)s*M_PTS + m)*9 + k)*H + t];
    c_lds[k*H + t] = v;
  }
  __syncthreads();
  #pragma unroll
  for (int li = 0; li < 9; ++li) {
    int l = (li == 0) ? 0 : (li < 4 ? 1 : 2);
    float invn = (l == 0) ? 1.0f : (l == 1 ? 0.57735026919f : 0.44721359550f);
    float a = 0.0f;
    for (int u = 0; u < H; ++u)
      a += c_lds[li*H + u] * W_up[(size_t)(l*H + u)*H + t];
    CU[((size_t)m*12 + li)*H + t] = a * invn;
  }
  #pragma unroll
  for (int li = 9; li < 12; ++li)
    CU[((size_t)m*12 + li)*H + t] = 0.0f;
}

// ---------------------------------------------------------------------------
// K4: up GEMM  out_pre[2048 x 128] = SH[2048 x 1536] @ CU[1536 x 128],
// split-K over 8 chunks of 192. Block tile 64n x 128w, thread tile 4n x 8w.
// ---------------------------------------------------------------------------
__global__ __launch_bounds__(256) void k_up(const float* __restrict__ SH,
    const float* __restrict__ CU, float* __restrict__ out_part) {
  __shared__ float At[32 * 68];    // [k][n] padded
  __shared__ float Bl[32 * 128];   // [k][w]
  int t = threadIdx.x;
  int n0 = blockIdx.x * 64;
  int ks = blockIdx.y;
  int tgn = t >> 4, tgw = t & 15;
  float acc[4][8] = {};
  for (int ch = 0; ch < 6; ++ch) {
    int kc = ks*192 + ch*32;
    #pragma unroll
    for (int i = 0; i < 2; ++i) {           // stage A (transposed)
      int idx = t + i*256;
      int n = idx >> 3, q = (idx & 7) << 2;
      float4 v = *(const float4*)(SH + (size_t)(n0 + n)*1536 + kc + q);
      At[(q+0)*68 + n] = v.x; At[(q+1)*68 + n] = v.y;
      At[(q+2)*68 + n] = v.z; At[(q+3)*68 + n] = v.w;
    }
    #pragma unroll
    for (int i = 0; i < 4; ++i) {           // stage B
      int idx = t + i*256;
      int k = idx >> 5, q = (idx & 31) << 2;
      *(float4*)&Bl[k*128 + q] = *(const float4*)(CU + (size_t)(kc + k)*H + q);
    }
    __syncthreads();
    #pragma unroll 4
    for (int k = 0; k < 32; ++k) {
      float4 a4 = *(const float4*)&At[k*68 + 4*tgn];
      float4 b0 = *(const float4*)&Bl[k*128 + 8*tgw];
      float4 b1 = *(const float4*)&Bl[k*128 + 8*tgw + 4];
      float av[4] = {a4.x, a4.y, a4.z, a4.w};
      float bvv[8] = {b0.x, b0.y, b0.z, b0.w, b1.x, b1.y, b1.z, b1.w};
      #pragma unroll
      for (int r = 0; r < 4; ++r)
        #pragma unroll
        for (int c = 0; c < 8; ++c)
          acc[r][c] += av[r] * bvv[c];
    }
    __syncthreads();
  }
  #pragma unroll
  for (int r = 0; r < 4; ++r) {
    size_t row = (size_t)ks*N_PTS + n0 + 4*tgn + r;
    *(float4*)(out_part + row*H + 8*tgw)     = make_float4(acc[r][0], acc[r][1], acc[r][2], acc[r][3]);
    *(float4*)(out_part + row*H + 8*tgw + 4) = make_float4(acc[r][4], acc[r][5], acc[r][6], acc[r][7]);
  }
}

// ---------------------------------------------------------------------------
// K5: reduce split-K partials, post-MLP (W_post + b_post) and silu -> d_out
// ---------------------------------------------------------------------------
__global__ __launch_bounds__(128) void k_post(const float* __restrict__ out_part,
    const float* __restrict__ W_post, const float* __restrict__ b_post,
    float* __restrict__ out) {
  __shared__ float op[8 * H];
  int t = threadIdx.x;
  int n0 = blockIdx.x * 8;
  #pragma unroll
  for (int n = 0; n < 8; ++n) {
    float v = 0.0f;
    #pragma unroll
    for (int s = 0; s < 8; ++s)
      v += out_part[((size_t)s*N_PTS + n0 + n)*H + t];
    op[n*H + t] = v;
  }
  __syncthreads();
  float acc[8] = {};
  for (int u = 0; u < H; ++u) {
    float wp = W_post[u*H + t];
    #pragma unroll
    for (int n = 0; n < 8; ++n)
      acc[n] += op[n*H + u] * wp;
  }
  float bp = b_post[t];
  #pragma unroll
  for (int n = 0; n < 8; ++n)
    out[(size_t)(n0 + n)*H + t] = silu_f(acc[n] + bp);
}

// ---------------------------------------------------------------------------
extern "C" void kernel_launch(void* const* d_in, const int* in_sizes, int n_in,
                              void* d_out, int out_size, void* d_ws, size_t ws_size,
                              hipStream_t stream) {
  const float* h      = (const float*)d_in[0];
  const float* gc     = (const float*)d_in[1];
  const float* cc     = (const float*)d_in[2];
  const float* gw     = (const float*)d_in[3];
  const float* W_pre  = (const float*)d_in[4];
  const float* b_pre  = (const float*)d_in[5];
  const float* W_down = (const float*)d_in[6];
  const float* W_up   = (const float*)d_in[7];
  const float* W_post = (const float*)d_in[8];
  const float* b_post = (const float*)d_in[9];

  float* ws       = (float*)d_ws;
  float* SH       = ws;                     // 2048*128*12      = 3,145,728 f
  float* hdg      = SH + 3145728;           // 3*2048*128       =   786,432 f
  float* c_part   = hdg + 786432;           // 16*128*9*128     = 2,359,296 f
  float* CU       = c_part + 2359296;       // 128*12*128       =   196,608 f
  float* out_part = CU + 196608;            // 8*2048*128       = 2,097,152 f
  float* out      = (float*)d_out;

  k_sh  <<<1024,        256, 0, stream>>>(gc, cc, SH);
  k_pre <<<256,         128, 0, stream>>>(h, W_pre, b_pre, W_down, gw, hdg);
  k_down<<<dim3(32,16), 128, 0, stream>>>(SH, hdg, c_part);
  k_cu  <<<128,         128, 0, stream>>>(c_part, W_up, CU);
  k_up  <<<dim3(32,8),  256, 0, stream>>>(SH, CU, out_part);
  k_post<<<256,         128, 0, stream>>>(out_part, W_post, b_post, out);
}